// Round 8
// baseline (9195.899 us; speedup 1.0000x reference)
//
#include <hip/hip_runtime.h>
#include <cstdint>

#define B_  64
#define T_  1024
#define I_  256
#define H_  512

typedef _Float16 h2_t __attribute__((ext_vector_type(2)));
typedef int sv16 __attribute__((ext_vector_type(16)));

__device__ __forceinline__ uint16_t f2h(float f) {
  _Float16 h = (_Float16)f;                        // v_cvt_f16_f32, RNE
  return __builtin_bit_cast(uint16_t, h);
}
__device__ __forceinline__ float dot2(uint32_t a, uint32_t b, float c) {
  return __builtin_amdgcn_fdot2(__builtin_bit_cast(h2_t, a),
                                __builtin_bit_cast(h2_t, b), c, false);
}
__device__ __forceinline__ float fast_tanh(float s) {
  float e = __expf(2.0f * s);
  return fmaf(-2.0f, __builtin_amdgcn_rcpf(e + 1.0f), 1.0f);
}

// select h pair P (0..63 within one h-quarter) from 4x16 SGPR vectors
template<int P>
__device__ __forceinline__ uint32_t hsel(sv16 h0, sv16 h1, sv16 h2, sv16 h3) {
  if constexpr (P < 16)      return (uint32_t)h0[P];
  else if constexpr (P < 32) return (uint32_t)h1[P - 16];
  else if constexpr (P < 48) return (uint32_t)h2[P - 32];
  else                       return (uint32_t)h3[P - 48];
}

// Pack ONE W_hh into f16-pair stream at ws[0:512KB).
// Layout: [k8 (64)][j (512)][m (4)] u32; u32 m at (k8,j) = (W[k][j],W[k+1][j]), k=8*k8+2m.
__global__ void pack_whh(const float* __restrict__ W, uint32_t* __restrict__ out) {
  int idx = blockIdx.x * 256 + threadIdx.x;        // [0, 131072)
  int k8 = idx >> 11;
  int j  = (idx >> 2) & 511;
  int m  = idx & 3;
  int k  = k8 * 8 + m * 2;
  uint32_t lo = f2h(W[k * H_ + j]);
  uint32_t hi = f2h(W[(k + 1) * H_ + j]);
  out[idx] = lo | (hi << 16);
}

// Y[tile rows] = A[tile rows] @ W + bias.  Tile = 64 rows x 512 cols, block 256.
// Rows staged fully into LDS before any write -> safe for in-place (A == Y).
template<int K>
__global__ __launch_bounds__(256) void gemm_rows(const float* A,
    const float* __restrict__ W, const float* __restrict__ bias,
    float* Y) {
  __shared__ float As[64 * (K + 1)];
  const int tid = threadIdx.x;
  const size_t row0 = (size_t)blockIdx.x * 64;
  const float* Ab = A + row0 * K;
  for (int idx = tid * 4; idx < 64 * K; idx += 1024) {
    float4 v = *(const float4*)(Ab + idx);
    int rr = idx / K;
    int cc = idx - rr * K;
    float* dst = &As[rr * (K + 1) + cc];
    dst[0] = v.x; dst[1] = v.y; dst[2] = v.z; dst[3] = v.w;
  }
  __syncthreads();
  const int cg = tid & 15;
  const int rg = tid >> 4;
  float acc[4][32];
  #pragma unroll
  for (int i = 0; i < 32; ++i) {
    float bz = bias[cg + 16 * i];
    acc[0][i] = bz; acc[1][i] = bz; acc[2][i] = bz; acc[3][i] = bz;
  }
  const float* Wc = W + cg;
  for (int k = 0; k < K; ++k) {
    float a0 = As[(rg * 4 + 0) * (K + 1) + k];
    float a1 = As[(rg * 4 + 1) * (K + 1) + k];
    float a2 = As[(rg * 4 + 2) * (K + 1) + k];
    float a3 = As[(rg * 4 + 3) * (K + 1) + k];
    const float* Wk = Wc + (size_t)k * H_;
    #pragma unroll
    for (int i = 0; i < 32; ++i) {
      float w = Wk[16 * i];
      acc[0][i] = fmaf(a0, w, acc[0][i]);
      acc[1][i] = fmaf(a1, w, acc[1][i]);
      acc[2][i] = fmaf(a2, w, acc[2][i]);
      acc[3][i] = fmaf(a3, w, acc[3][i]);
    }
  }
  float* Yb = Y + row0 * H_;
  #pragma unroll
  for (int jj = 0; jj < 4; ++jj) {
    float* Yr = Yb + (size_t)(rg * 4 + jj) * H_ + cg;
    #pragma unroll
    for (int i = 0; i < 32; ++i) Yr[16 * i] = acc[jj][i];
  }
}

// ROW: one uint4 of W (8 k = 4 pairs) against h pairs 4m..4m+3, 4 acc chains.
#define ROW(m, WEXPR) { uint4 w_ = (WEXPR); \
  a0 = dot2(w_.x, hsel<4*(m)+0>(h0,h1,h2,h3), a0); \
  a1 = dot2(w_.y, hsel<4*(m)+1>(h0,h1,h2,h3), a1); \
  a2 = dot2(w_.z, hsel<4*(m)+2>(h0,h1,h2,h3), a2); \
  a3 = dot2(w_.w, hsel<4*(m)+3>(h0,h1,h2,h3), a3); }

// Load one h-quarter (128 f16 = 4 x s_load_dwordx16) into SGPRs.
// SINGLE asm block with the lgkmcnt(0) wait INSIDE and =&s early-clobber
// outputs: no compiler-inserted SGPR copy can observe an incomplete load,
// and no output range can alias the base-address input pair.
#define BATCH_LOAD(OFF0, OFF1, OFF2, OFF3) \
  asm volatile("s_load_dwordx16 %0, %4, " OFF0 "\n\t" \
               "s_load_dwordx16 %1, %4, " OFF1 "\n\t" \
               "s_load_dwordx16 %2, %4, " OFF2 "\n\t" \
               "s_load_dwordx16 %3, %4, " OFF3 "\n\t" \
               "s_waitcnt lgkmcnt(0)" \
               : "=&s"(h0), "=&s"(h1), "=&s"(h2), "=&s"(h3) : "s"(hbase)); \
  __builtin_amdgcn_sched_barrier(0);

// Quarter consume: 12 streamed slabs + 4 LDS slabs.
// ROW(m) sees slab k8 = 16q+m: streamed m=0..11, LDS m=12..15.
#define CONSQ(q, G) \
  ROW(0,  G[0])  ROW(1,  G[1])  ROW(2,  G[2])  ROW(3,  G[3]) \
  ROW(4,  G[4])  ROW(5,  G[5])  ROW(6,  G[6])  ROW(7,  G[7]) \
  ROW(8,  G[8])  ROW(9,  G[9])  ROW(10, G[10]) ROW(11, G[11]) \
  ROW(12, WL[(4*(q)+0)*512 + j]) ROW(13, WL[(4*(q)+1)*512 + j]) \
  ROW(14, WL[(4*(q)+2)*512 + j]) ROW(15, WL[(4*(q)+3)*512 + j])

// Persistent scan: one WG per batch, thread j owns hidden unit j.
// h broadcast via SGPRs (global ping-pong round-trip + s_load_dwordx16 after
// s_dcache_inv; ping-pong kills the R4 WAR race).
// W: NO VGPR pinning (R2/R6/R7 evidence: the allocator targets 128 VGPRs and
// spills any pinned excess to scratch, poisoning the stream). Instead:
//   16 slabs resident in 128KB LDS (parallel pipe, proven R7),
//   48 slabs streamed from L2 each step (384KB -> ~3072 cyc at the per-CU
//   128 B/cyc VMEM ceiling that bounded R2), double-buffered gA/gB (96 VGPRs),
//   issued one quarter ahead so latency+sync hide under the stream.
// Slab map per quarter q: streamed = k8 in [16q,16q+12), LDS = [16q+12,16q+16).
__global__ __launch_bounds__(512, 2) void rnn_scan(float* Y,
    const uint4* __restrict__ Wp, ushort* __restrict__ hb16,
    float* __restrict__ hn) {
  __shared__ uint4 WL[16 * 512];                   // 128 KB
  const int j = threadIdx.x;
  float* Yb = Y + (size_t)blockIdx.x * (T_ * H_);
  ushort* hp0 = hb16 + blockIdx.x * (2 * H_);      // ping
  ushort* hp1 = hp0 + H_;                          // pong

  // LDS W: quarter q slabs 12..15 -> WL[4q .. 4q+3]
  #pragma unroll
  for (int q = 0; q < 4; ++q)
    #pragma unroll
    for (int l = 0; l < 4; ++l)
      WL[(4 * q + l) * 512 + j] = Wp[(16 * q + 12 + l) * H_ + j];

  // t = 0: h_prev = 0 -> h = tanh(xp); h(0) -> buf0
  float xp0 = Yb[j];
  float v = fast_tanh(xp0);
  hp0[j] = f2h(v);
  Yb[j] = v;
  const uint64_t hb0 = (uint64_t)(uintptr_t)hp0;
  const uint64_t hb1 = (uint64_t)(uintptr_t)hp1;
  // drain h store (vm) + WL ds_writes (lgkm), sync, invalidate K$
  asm volatile("s_waitcnt vmcnt(0) lgkmcnt(0)\n\ts_barrier\n\ts_dcache_inv" ::: "memory");

  const uint4* WpS = Wp + j;                       // + slab*H_ per access

  for (int t = 1; t < T_; ++t) {
    const uint64_t hbase = (t & 1) ? hb0 : hb1;    // read h(t-1) from buf[(t-1)&1]
    ushort* hst = (t & 1) ? hp1 : hp0;             // store h(t) to buf[t&1]
    float xpt = Yb[t * H_ + j];
    float a0 = 0.f, a1 = 0.f, a2 = 0.f, a3 = 0.f;
    sv16 h0, h1, h2, h3;
    uint4 gA[12], gB[12];
    #pragma unroll
    for (int s = 0; s < 12; ++s) gA[s] = WpS[(0 + s) * H_];   // q0 streamed

    BATCH_LOAD("0x0", "0x40", "0x80", "0xc0")      // h quarter 0
    #pragma unroll
    for (int s = 0; s < 12; ++s) gB[s] = WpS[(16 + s) * H_];  // q1 streamed
    CONSQ(0, gA)

    BATCH_LOAD("0x100", "0x140", "0x180", "0x1c0") // h quarter 1
    #pragma unroll
    for (int s = 0; s < 12; ++s) gA[s] = WpS[(32 + s) * H_];  // q2 streamed
    CONSQ(1, gB)

    BATCH_LOAD("0x200", "0x240", "0x280", "0x2c0") // h quarter 2
    #pragma unroll
    for (int s = 0; s < 12; ++s) gB[s] = WpS[(48 + s) * H_];  // q3 streamed
    CONSQ(2, gA)

    BATCH_LOAD("0x300", "0x340", "0x380", "0x3c0") // h quarter 3
    CONSQ(3, gB)

    float s = xpt + ((a0 + a1) + (a2 + a3));
    v = fast_tanh(s);
    hst[j] = f2h(v);
    // h store must be L2-visible before other waves' next-step s_loads
    asm volatile("s_waitcnt vmcnt(0)\n\ts_barrier\n\ts_dcache_inv" ::: "memory");
    Yb[t * H_ + j] = v;                            // drains under next step's compute
  }
  hn[blockIdx.x * H_ + j] = v;
}

extern "C" void kernel_launch(void* const* d_in, const int* in_sizes, int n_in,
                              void* d_out, int out_size, void* d_ws, size_t ws_size,
                              hipStream_t stream) {
  const float* x     = (const float*)d_in[0];
  const float* W_ih0 = (const float*)d_in[1];
  const float* W_hh0 = (const float*)d_in[2];
  const float* b0    = (const float*)d_in[3];
  const float* W_ih1 = (const float*)d_in[4];
  const float* W_hh1 = (const float*)d_in[5];
  const float* b1    = (const float*)d_in[6];

  float* Y  = (float*)d_out;                        // [64][1024][512]
  float* hn = Y + (size_t)B_ * T_ * H_;             // [2][64][512]
  uint32_t* Wp = (uint32_t*)d_ws;                   // [0,512KB): f16-packed W_hh (one layer at a time)
  ushort* hbuf = (ushort*)((char*)d_ws + 512 * 1024); // [512KB,640KB): per-block ping-pong h (f16)

  // layer 0
  pack_whh<<<512, 256, 0, stream>>>(W_hh0, Wp);
  gemm_rows<I_><<<1024, 256, 0, stream>>>(x, W_ih0, b0, Y);
  rnn_scan<<<B_, H_, 0, stream>>>(Y, (const uint4*)Wp, hbuf, hn);
  // layer 1 (re-pack Wp with W_hh1 after scan0 is done with it)
  pack_whh<<<512, 256, 0, stream>>>(W_hh1, Wp);
  gemm_rows<H_><<<1024, 256, 0, stream>>>(Y, W_ih1, b1, Y);
  rnn_scan<<<B_, H_, 0, stream>>>(Y, (const uint4*)Wp, hbuf, hn + B_ * H_);
}

// Round 9
// 7015.213 us; speedup vs baseline: 1.3109x; 1.3109x over previous
//
#include <hip/hip_runtime.h>
#include <cstdint>

#define B_  64
#define T_  1024
#define I_  256
#define H_  512

typedef _Float16 h2_t __attribute__((ext_vector_type(2)));
typedef int sv16 __attribute__((ext_vector_type(16)));

__device__ __forceinline__ uint16_t f2h(float f) {
  _Float16 h = (_Float16)f;                        // v_cvt_f16_f32, RNE
  return __builtin_bit_cast(uint16_t, h);
}
__device__ __forceinline__ float dot2(uint32_t a, uint32_t b, float c) {
  return __builtin_amdgcn_fdot2(__builtin_bit_cast(h2_t, a),
                                __builtin_bit_cast(h2_t, b), c, false);
}
__device__ __forceinline__ float fast_tanh(float s) {
  float e = __expf(2.0f * s);
  return fmaf(-2.0f, __builtin_amdgcn_rcpf(e + 1.0f), 1.0f);
}

// select h pair P (0..63 within one h-quarter) from 4x16 SGPR vectors
template<int P>
__device__ __forceinline__ uint32_t hsel(sv16 h0, sv16 h1, sv16 h2, sv16 h3) {
  if constexpr (P < 16)      return (uint32_t)h0[P];
  else if constexpr (P < 32) return (uint32_t)h1[P - 16];
  else if constexpr (P < 48) return (uint32_t)h2[P - 32];
  else                       return (uint32_t)h3[P - 48];
}

// Pack ONE W_hh into f16-pair stream at ws[0:512KB).
// Layout: [k8 (64)][j (512)][m (4)] u32; u32 m at (k8,j) = (W[k][j],W[k+1][j]), k=8*k8+2m.
__global__ void pack_whh(const float* __restrict__ W, uint32_t* __restrict__ out) {
  int idx = blockIdx.x * 256 + threadIdx.x;        // [0, 131072)
  int k8 = idx >> 11;
  int j  = (idx >> 2) & 511;
  int m  = idx & 3;
  int k  = k8 * 8 + m * 2;
  uint32_t lo = f2h(W[k * H_ + j]);
  uint32_t hi = f2h(W[(k + 1) * H_ + j]);
  out[idx] = lo | (hi << 16);
}

// Y[tile rows] = A[tile rows] @ W + bias.  Tile = 64 rows x 512 cols, block 256.
// Rows staged fully into LDS before any write -> safe for in-place (A == Y).
template<int K>
__global__ __launch_bounds__(256) void gemm_rows(const float* A,
    const float* __restrict__ W, const float* __restrict__ bias,
    float* Y) {
  __shared__ float As[64 * (K + 1)];
  const int tid = threadIdx.x;
  const size_t row0 = (size_t)blockIdx.x * 64;
  const float* Ab = A + row0 * K;
  for (int idx = tid * 4; idx < 64 * K; idx += 1024) {
    float4 v = *(const float4*)(Ab + idx);
    int rr = idx / K;
    int cc = idx - rr * K;
    float* dst = &As[rr * (K + 1) + cc];
    dst[0] = v.x; dst[1] = v.y; dst[2] = v.z; dst[3] = v.w;
  }
  __syncthreads();
  const int cg = tid & 15;
  const int rg = tid >> 4;
  float acc[4][32];
  #pragma unroll
  for (int i = 0; i < 32; ++i) {
    float bz = bias[cg + 16 * i];
    acc[0][i] = bz; acc[1][i] = bz; acc[2][i] = bz; acc[3][i] = bz;
  }
  const float* Wc = W + cg;
  for (int k = 0; k < K; ++k) {
    float a0 = As[(rg * 4 + 0) * (K + 1) + k];
    float a1 = As[(rg * 4 + 1) * (K + 1) + k];
    float a2 = As[(rg * 4 + 2) * (K + 1) + k];
    float a3 = As[(rg * 4 + 3) * (K + 1) + k];
    const float* Wk = Wc + (size_t)k * H_;
    #pragma unroll
    for (int i = 0; i < 32; ++i) {
      float w = Wk[16 * i];
      acc[0][i] = fmaf(a0, w, acc[0][i]);
      acc[1][i] = fmaf(a1, w, acc[1][i]);
      acc[2][i] = fmaf(a2, w, acc[2][i]);
      acc[3][i] = fmaf(a3, w, acc[3][i]);
    }
  }
  float* Yb = Y + row0 * H_;
  #pragma unroll
  for (int jj = 0; jj < 4; ++jj) {
    float* Yr = Yb + (size_t)(rg * 4 + jj) * H_ + cg;
    #pragma unroll
    for (int i = 0; i < 32; ++i) Yr[16 * i] = acc[jj][i];
  }
}

// ROW: one uint4 of W (8 k = 4 pairs) against h pairs 4m..4m+3, 4 acc chains.
#define ROW(m, WEXPR) { uint4 w_ = (WEXPR); \
  a0 = dot2(w_.x, hsel<4*(m)+0>(h0,h1,h2,h3), a0); \
  a1 = dot2(w_.y, hsel<4*(m)+1>(h0,h1,h2,h3), a1); \
  a2 = dot2(w_.z, hsel<4*(m)+2>(h0,h1,h2,h3), a2); \
  a3 = dot2(w_.w, hsel<4*(m)+3>(h0,h1,h2,h3), a3); }

// Load one h-quarter (128 f16 = 4 x s_load_dwordx16) into SGPRs.
// SINGLE asm block with the lgkmcnt(0) wait INSIDE and =&s early-clobber
// outputs: no compiler-inserted SGPR copy can observe an incomplete load,
// and no output range can alias the base-address input pair.
#define BATCH_LOAD(OFF0, OFF1, OFF2, OFF3) \
  asm volatile("s_load_dwordx16 %0, %4, " OFF0 "\n\t" \
               "s_load_dwordx16 %1, %4, " OFF1 "\n\t" \
               "s_load_dwordx16 %2, %4, " OFF2 "\n\t" \
               "s_load_dwordx16 %3, %4, " OFF3 "\n\t" \
               "s_waitcnt lgkmcnt(0)" \
               : "=&s"(h0), "=&s"(h1), "=&s"(h2), "=&s"(h3) : "s"(hbase)); \
  __builtin_amdgcn_sched_barrier(0);

// Quarter consume: 8 "preload" slabs + 4 LDS slabs + 4 streamed slabs.
// ROW(m) sees slab k8 = 16q+m: wrv m<8, LDS m=8..11, streamed m=12..15.
#define CONSQ(q, G) \
  ROW(0,  wrv[8*(q)+0])  ROW(1,  wrv[8*(q)+1])  ROW(2,  wrv[8*(q)+2]) \
  ROW(3,  wrv[8*(q)+3])  ROW(4,  wrv[8*(q)+4])  ROW(5,  wrv[8*(q)+5]) \
  ROW(6,  wrv[8*(q)+6])  ROW(7,  wrv[8*(q)+7]) \
  ROW(8,  WL[(4*(q)+0)*512 + j]) ROW(9,  WL[(4*(q)+1)*512 + j]) \
  ROW(10, WL[(4*(q)+2)*512 + j]) ROW(11, WL[(4*(q)+3)*512 + j]) \
  ROW(12, G[0]) ROW(13, G[1]) ROW(14, G[2]) ROW(15, G[3])

// Persistent scan: one WG per batch, thread j owns hidden unit j.
// h broadcast via SGPRs (global ping-pong round-trip + s_load_dwordx16 after
// s_dcache_inv; ping-pong kills the R4 WAR race).
// Structure = R2's (the 1584us best): wrv "preload" UNPINNED -- the compiler
// may sink the loads into the loop and self-schedule the stream (R2 behavior)
// or, with the relaxed __launch_bounds__(512,1) (the one new lever: the old
// ",2" coincided with a hard 128-VGPR allocator target in R2/R6/R7/R8),
// genuinely keep slabs resident in up to 256 VGPRs.
// 16 slabs LDS-resident; 16 explicitly streamed, issued one quarter early.
__global__ __launch_bounds__(512, 1) void rnn_scan(float* Y,
    const uint4* __restrict__ Wp, ushort* __restrict__ hb16,
    float* __restrict__ hn) {
  __shared__ uint4 WL[16 * 512];                   // 128 KB
  const int j = threadIdx.x;
  float* Yb = Y + (size_t)blockIdx.x * (T_ * H_);
  ushort* hp0 = hb16 + blockIdx.x * (2 * H_);      // ping
  ushort* hp1 = hp0 + H_;                          // pong

  // "preload" W: quarter q slabs 0..7 -> wrv[8q..8q+7] (allocator's choice)
  uint4 wrv[32];
  #pragma unroll
  for (int q = 0; q < 4; ++q)
    #pragma unroll
    for (int r = 0; r < 8; ++r)
      wrv[8 * q + r] = Wp[(16 * q + r) * H_ + j];
  // LDS W: quarter q slabs 8..11 -> WL[4q..4q+3]
  #pragma unroll
  for (int q = 0; q < 4; ++q)
    #pragma unroll
    for (int l = 0; l < 4; ++l)
      WL[(4 * q + l) * 512 + j] = Wp[(16 * q + 8 + l) * H_ + j];

  // t = 0: h_prev = 0 -> h = tanh(xp); h(0) -> buf0
  float xp0 = Yb[j];
  float v = fast_tanh(xp0);
  hp0[j] = f2h(v);
  Yb[j] = v;
  const uint64_t hb0 = (uint64_t)(uintptr_t)hp0;
  const uint64_t hb1 = (uint64_t)(uintptr_t)hp1;
  // drain h store (vm) + WL ds_writes (lgkm), sync, invalidate K$
  asm volatile("s_waitcnt vmcnt(0) lgkmcnt(0)\n\ts_barrier\n\ts_dcache_inv" ::: "memory");

  const uint4* WpS = Wp + j;                       // + slab*H_ per access

  for (int t = 1; t < T_; ++t) {
    const uint64_t hbase = (t & 1) ? hb0 : hb1;    // read h(t-1) from buf[(t-1)&1]
    ushort* hst = (t & 1) ? hp1 : hp0;             // store h(t) to buf[t&1]
    float xpt = Yb[t * H_ + j];
    float a0 = 0.f, a1 = 0.f, a2 = 0.f, a3 = 0.f;
    sv16 h0, h1, h2, h3;
    uint4 gA[4], gB[4];
    #pragma unroll
    for (int s = 0; s < 4; ++s) gA[s] = WpS[(12 + s) * H_];   // q0 streamed

    BATCH_LOAD("0x0", "0x40", "0x80", "0xc0")      // h quarter 0
    #pragma unroll
    for (int s = 0; s < 4; ++s) gB[s] = WpS[(28 + s) * H_];   // q1 streamed
    CONSQ(0, gA)

    BATCH_LOAD("0x100", "0x140", "0x180", "0x1c0") // h quarter 1
    #pragma unroll
    for (int s = 0; s < 4; ++s) gA[s] = WpS[(44 + s) * H_];   // q2 streamed
    CONSQ(1, gB)

    BATCH_LOAD("0x200", "0x240", "0x280", "0x2c0") // h quarter 2
    #pragma unroll
    for (int s = 0; s < 4; ++s) gB[s] = WpS[(60 + s) * H_];   // q3 streamed
    CONSQ(2, gA)

    BATCH_LOAD("0x300", "0x340", "0x380", "0x3c0") // h quarter 3
    CONSQ(3, gB)

    float s = xpt + ((a0 + a1) + (a2 + a3));
    v = fast_tanh(s);
    hst[j] = f2h(v);
    // h store must be L2-visible before other waves' next-step s_loads
    asm volatile("s_waitcnt vmcnt(0)\n\ts_barrier\n\ts_dcache_inv" ::: "memory");
    Yb[t * H_ + j] = v;                            // drains under next step's compute
  }
  hn[blockIdx.x * H_ + j] = v;
}

extern "C" void kernel_launch(void* const* d_in, const int* in_sizes, int n_in,
                              void* d_out, int out_size, void* d_ws, size_t ws_size,
                              hipStream_t stream) {
  const float* x     = (const float*)d_in[0];
  const float* W_ih0 = (const float*)d_in[1];
  const float* W_hh0 = (const float*)d_in[2];
  const float* b0    = (const float*)d_in[3];
  const float* W_ih1 = (const float*)d_in[4];
  const float* W_hh1 = (const float*)d_in[5];
  const float* b1    = (const float*)d_in[6];

  float* Y  = (float*)d_out;                        // [64][1024][512]
  float* hn = Y + (size_t)B_ * T_ * H_;             // [2][64][512]
  uint32_t* Wp = (uint32_t*)d_ws;                   // [0,512KB): f16-packed W_hh (one layer at a time)
  ushort* hbuf = (ushort*)((char*)d_ws + 512 * 1024); // [512KB,640KB): per-block ping-pong h (f16)

  // layer 0
  pack_whh<<<512, 256, 0, stream>>>(W_hh0, Wp);
  gemm_rows<I_><<<1024, 256, 0, stream>>>(x, W_ih0, b0, Y);
  rnn_scan<<<B_, H_, 0, stream>>>(Y, (const uint4*)Wp, hbuf, hn);
  // layer 1 (re-pack Wp with W_hh1 after scan0 is done with it)
  pack_whh<<<512, 256, 0, stream>>>(W_hh1, Wp);
  gemm_rows<H_><<<1024, 256, 0, stream>>>(Y, W_ih1, b1, Y);
  rnn_scan<<<B_, H_, 0, stream>>>(Y, (const uint4*)Wp, hbuf, hn + B_ * H_);
}

// Round 10
// 4103.136 us; speedup vs baseline: 2.2412x; 1.7097x over previous
//
#include <hip/hip_runtime.h>
#include <cstdint>

#define B_  64
#define T_  1024
#define I_  256
#define H_  512

typedef _Float16 h2_t __attribute__((ext_vector_type(2)));
typedef int sv16 __attribute__((ext_vector_type(16)));

__device__ __forceinline__ uint16_t f2h(float f) {
  _Float16 h = (_Float16)f;                        // v_cvt_f16_f32, RNE
  return __builtin_bit_cast(uint16_t, h);
}
__device__ __forceinline__ float dot2(uint32_t a, uint32_t b, float c) {
  return __builtin_amdgcn_fdot2(__builtin_bit_cast(h2_t, a),
                                __builtin_bit_cast(h2_t, b), c, false);
}
__device__ __forceinline__ float fast_tanh(float s) {
  float e = __expf(2.0f * s);
  return fmaf(-2.0f, __builtin_amdgcn_rcpf(e + 1.0f), 1.0f);
}

// select h pair P (0..63 within one h-quarter) from 4x16 SGPR vectors
template<int P>
__device__ __forceinline__ uint32_t hsel(sv16 h0, sv16 h1, sv16 h2, sv16 h3) {
  if constexpr (P < 16)      return (uint32_t)h0[P];
  else if constexpr (P < 32) return (uint32_t)h1[P - 16];
  else if constexpr (P < 48) return (uint32_t)h2[P - 32];
  else                       return (uint32_t)h3[P - 48];
}

// Pack ONE W_hh into f16-pair stream at ws[0:512KB).
// Layout: [k8 (64)][j (512)][m (4)] u32; u32 m at (k8,j) = (W[k][j],W[k+1][j]), k=8*k8+2m.
__global__ void pack_whh(const float* __restrict__ W, uint32_t* __restrict__ out) {
  int idx = blockIdx.x * 256 + threadIdx.x;        // [0, 131072)
  int k8 = idx >> 11;
  int j  = (idx >> 2) & 511;
  int m  = idx & 3;
  int k  = k8 * 8 + m * 2;
  uint32_t lo = f2h(W[k * H_ + j]);
  uint32_t hi = f2h(W[(k + 1) * H_ + j]);
  out[idx] = lo | (hi << 16);
}

// Y[tile rows] = A[tile rows] @ W + bias.  Tile = 64 rows x 512 cols, block 256.
// Rows staged fully into LDS before any write -> safe for in-place (A == Y).
template<int K>
__global__ __launch_bounds__(256) void gemm_rows(const float* A,
    const float* __restrict__ W, const float* __restrict__ bias,
    float* Y) {
  __shared__ float As[64 * (K + 1)];
  const int tid = threadIdx.x;
  const size_t row0 = (size_t)blockIdx.x * 64;
  const float* Ab = A + row0 * K;
  for (int idx = tid * 4; idx < 64 * K; idx += 1024) {
    float4 v = *(const float4*)(Ab + idx);
    int rr = idx / K;
    int cc = idx - rr * K;
    float* dst = &As[rr * (K + 1) + cc];
    dst[0] = v.x; dst[1] = v.y; dst[2] = v.z; dst[3] = v.w;
  }
  __syncthreads();
  const int cg = tid & 15;
  const int rg = tid >> 4;
  float acc[4][32];
  #pragma unroll
  for (int i = 0; i < 32; ++i) {
    float bz = bias[cg + 16 * i];
    acc[0][i] = bz; acc[1][i] = bz; acc[2][i] = bz; acc[3][i] = bz;
  }
  const float* Wc = W + cg;
  for (int k = 0; k < K; ++k) {
    float a0 = As[(rg * 4 + 0) * (K + 1) + k];
    float a1 = As[(rg * 4 + 1) * (K + 1) + k];
    float a2 = As[(rg * 4 + 2) * (K + 1) + k];
    float a3 = As[(rg * 4 + 3) * (K + 1) + k];
    const float* Wk = Wc + (size_t)k * H_;
    #pragma unroll
    for (int i = 0; i < 32; ++i) {
      float w = Wk[16 * i];
      acc[0][i] = fmaf(a0, w, acc[0][i]);
      acc[1][i] = fmaf(a1, w, acc[1][i]);
      acc[2][i] = fmaf(a2, w, acc[2][i]);
      acc[3][i] = fmaf(a3, w, acc[3][i]);
    }
  }
  float* Yb = Y + row0 * H_;
  #pragma unroll
  for (int jj = 0; jj < 4; ++jj) {
    float* Yr = Yb + (size_t)(rg * 4 + jj) * H_ + cg;
    #pragma unroll
    for (int i = 0; i < 32; ++i) Yr[16 * i] = acc[jj][i];
  }
}

// ROW: one uint4 of W (8 k = 4 pairs) against h pairs 4m..4m+3, 4 acc chains.
#define ROW(m, WEXPR) { uint4 w_ = (WEXPR); \
  a0 = dot2(w_.x, hsel<4*(m)+0>(h0,h1,h2,h3), a0); \
  a1 = dot2(w_.y, hsel<4*(m)+1>(h0,h1,h2,h3), a1); \
  a2 = dot2(w_.z, hsel<4*(m)+2>(h0,h1,h2,h3), a2); \
  a3 = dot2(w_.w, hsel<4*(m)+3>(h0,h1,h2,h3), a3); }

// Load one h-quarter (128 f16 = 4 x s_load_dwordx16) into SGPRs.
// SINGLE asm block with the lgkmcnt(0) wait INSIDE and =&s early-clobber
// outputs: no compiler-inserted SGPR copy can observe an incomplete load,
// and no output range can alias the base-address input pair (the R3 NaN bug).
#define BATCH_LOAD(OFF0, OFF1, OFF2, OFF3) \
  asm volatile("s_load_dwordx16 %0, %4, " OFF0 "\n\t" \
               "s_load_dwordx16 %1, %4, " OFF1 "\n\t" \
               "s_load_dwordx16 %2, %4, " OFF2 "\n\t" \
               "s_load_dwordx16 %3, %4, " OFF3 "\n\t" \
               "s_waitcnt lgkmcnt(0)" \
               : "=&s"(h0), "=&s"(h1), "=&s"(h2), "=&s"(h3) : "s"(hbase)); \
  __builtin_amdgcn_sched_barrier(0);

#define CONS16(W0)  ROW(0,W0(0))  ROW(1,W0(1))  ROW(2,W0(2))  ROW(3,W0(3)) \
                    ROW(4,W0(4))  ROW(5,W0(5))  ROW(6,W0(6))  ROW(7,W0(7)) \
                    ROW(8,W0(8))  ROW(9,W0(9))  ROW(10,W0(10)) ROW(11,W0(11)) \
                    ROW(12,W0(12)) ROW(13,W0(13)) ROW(14,W0(14)) ROW(15,W0(15))

#define WREG0(m) wrv[m]          // slabs  0..15 (compiler-managed)
#define WREG1(m) wrv[16 + (m)]   // slabs 16..31 (compiler-managed)
#define WLDS(m)  WL[(m) * 512 + j]  // slabs 32..47 (LDS-resident)
#define WSTR(m)  g[m]            // slabs 48..63 (explicit loop-top stream)

// Persistent scan: one WG per batch, thread j owns hidden unit j.
// h broadcast via SGPRs (global PING-PONG round-trip + s_load_dwordx16 after
// s_dcache_inv; ping-pong kills the R4 WAR race).
// R2's exact consume topology (the 1584us best): ALL compiler-managed W
// (wrv[32], loads sunk into the loop by the allocator) consumed in the FIRST
// TWO quarters -- their loads need cross only zero/one sched_barrier and can
// issue at the top of the step, deeply pipelined. LDS slabs in quarter 2
// (ds pipe, parallel). Explicit g[16] issued at loop top, consumed last.
// R7/R9's per-quarter interleave broke this (loads trapped behind 3 barriers).
__global__ __launch_bounds__(512, 2) void rnn_scan(float* Y,
    const uint4* __restrict__ Wp, ushort* __restrict__ hb16,
    float* __restrict__ hn) {
  __shared__ uint4 WL[16 * 512];                   // 128 KB: slabs 32..47
  const int j = threadIdx.x;
  float* Yb = Y + (size_t)blockIdx.x * (T_ * H_);
  ushort* hp0 = hb16 + blockIdx.x * (2 * H_);      // ping
  ushort* hp1 = hp0 + H_;                          // pong

  // "preload" W slabs 0..31 (allocator will sink these into the loop; that is
  // the FAST behavior -- R2/R6/R7 proved forcing residency only causes spill)
  uint4 wrv[32];
  #pragma unroll
  for (int m = 0; m < 32; ++m) wrv[m] = Wp[m * H_ + j];
  #pragma unroll
  for (int it = 0; it < 16; ++it) WL[it * 512 + j] = Wp[(32 + it) * 512 + j];

  // t = 0: h_prev = 0 -> h = tanh(xp); h(0) -> buf0
  float xp0 = Yb[j];
  float v = fast_tanh(xp0);
  hp0[j] = f2h(v);
  Yb[j] = v;
  const uint64_t hb0 = (uint64_t)(uintptr_t)hp0;
  const uint64_t hb1 = (uint64_t)(uintptr_t)hp1;
  // drain h store (vm) + WL ds_writes (lgkm), sync, invalidate K$
  asm volatile("s_waitcnt vmcnt(0) lgkmcnt(0)\n\ts_barrier\n\ts_dcache_inv" ::: "memory");

  for (int t = 1; t < T_; ++t) {
    const uint64_t hbase = (t & 1) ? hb0 : hb1;    // read h(t-1) from buf[(t-1)&1]
    ushort* hst = (t & 1) ? hp1 : hp0;             // store h(t) to buf[t&1]
    float xpt = Yb[t * H_ + j];
    uint4 g[16];                                   // streamed slabs 48..63, loop-top issue
    #pragma unroll
    for (int m = 0; m < 16; ++m) g[m] = Wp[(48 + m) * H_ + j];
    float a0 = 0.f, a1 = 0.f, a2 = 0.f, a3 = 0.f;
    sv16 h0, h1, h2, h3;

    BATCH_LOAD("0x0", "0x40", "0x80", "0xc0")      // h quarter 0
    CONS16(WREG0)
    BATCH_LOAD("0x100", "0x140", "0x180", "0x1c0") // h quarter 1
    CONS16(WREG1)
    BATCH_LOAD("0x200", "0x240", "0x280", "0x2c0") // h quarter 2
    CONS16(WLDS)
    BATCH_LOAD("0x300", "0x340", "0x380", "0x3c0") // h quarter 3
    CONS16(WSTR)

    float s = xpt + ((a0 + a1) + (a2 + a3));
    v = fast_tanh(s);
    hst[j] = f2h(v);
    // h store must be L2-visible before other waves' next-step s_loads
    asm volatile("s_waitcnt vmcnt(0)\n\ts_barrier\n\ts_dcache_inv" ::: "memory");
    Yb[t * H_ + j] = v;                            // drains under next step's compute
  }
  hn[blockIdx.x * H_ + j] = v;
}

extern "C" void kernel_launch(void* const* d_in, const int* in_sizes, int n_in,
                              void* d_out, int out_size, void* d_ws, size_t ws_size,
                              hipStream_t stream) {
  const float* x     = (const float*)d_in[0];
  const float* W_ih0 = (const float*)d_in[1];
  const float* W_hh0 = (const float*)d_in[2];
  const float* b0    = (const float*)d_in[3];
  const float* W_ih1 = (const float*)d_in[4];
  const float* W_hh1 = (const float*)d_in[5];
  const float* b1    = (const float*)d_in[6];

  float* Y  = (float*)d_out;                        // [64][1024][512]
  float* hn = Y + (size_t)B_ * T_ * H_;             // [2][64][512]
  uint32_t* Wp = (uint32_t*)d_ws;                   // [0,512KB): f16-packed W_hh (one layer at a time)
  ushort* hbuf = (ushort*)((char*)d_ws + 512 * 1024); // [512KB,640KB): per-block ping-pong h (f16)

  // layer 0
  pack_whh<<<512, 256, 0, stream>>>(W_hh0, Wp);
  gemm_rows<I_><<<1024, 256, 0, stream>>>(x, W_ih0, b0, Y);
  rnn_scan<<<B_, H_, 0, stream>>>(Y, (const uint4*)Wp, hbuf, hn);
  // layer 1 (re-pack Wp with W_hh1 after scan0 is done with it)
  pack_whh<<<512, 256, 0, stream>>>(W_hh1, Wp);
  gemm_rows<H_><<<1024, 256, 0, stream>>>(Y, W_ih1, b1, Y);
  rnn_scan<<<B_, H_, 0, stream>>>(Y, (const uint4*)Wp, hbuf, hn + B_ * H_);
}

// Round 11
// 3351.843 us; speedup vs baseline: 2.7435x; 1.2241x over previous
//
#include <hip/hip_runtime.h>
#include <cstdint>

#define B_  64
#define T_  1024
#define I_  256
#define H_  512

typedef _Float16 h2_t __attribute__((ext_vector_type(2)));
typedef int sv16 __attribute__((ext_vector_type(16)));
typedef _Float16 f16x8 __attribute__((ext_vector_type(8)));
typedef float f32x4 __attribute__((ext_vector_type(4)));

__device__ __forceinline__ uint32_t f2h(float f) {
  _Float16 h = (_Float16)f;                        // v_cvt_f16_f32, RNE
  return (uint32_t)__builtin_bit_cast(uint16_t, h);
}
__device__ __forceinline__ float dot2(uint32_t a, uint32_t b, float c) {
  return __builtin_amdgcn_fdot2(__builtin_bit_cast(h2_t, a),
                                __builtin_bit_cast(h2_t, b), c, false);
}
__device__ __forceinline__ float fast_tanh(float s) {
  float e = __expf(2.0f * s);
  return fmaf(-2.0f, __builtin_amdgcn_rcpf(e + 1.0f), 1.0f);
}

// select h pair P (0..63 within one h-quarter) from 4x16 SGPR vectors
template<int P>
__device__ __forceinline__ uint32_t hsel(sv16 h0, sv16 h1, sv16 h2, sv16 h3) {
  if constexpr (P < 16)      return (uint32_t)h0[P];
  else if constexpr (P < 32) return (uint32_t)h1[P - 16];
  else if constexpr (P < 48) return (uint32_t)h2[P - 32];
  else                       return (uint32_t)h3[P - 48];
}

// ---------- W_hh pack (scan weights), unchanged layout ----------
// [k8 (64)][j (512)][m (4)] u32; u32 m at (k8,j) = (W[k][j],W[k+1][j]), k=8*k8+2m.
__global__ void pack_whh(const float* __restrict__ W, uint32_t* __restrict__ out) {
  int idx = blockIdx.x * 256 + threadIdx.x;        // [0, 131072)
  int k8 = idx >> 11;
  int j  = (idx >> 2) & 511;
  int m  = idx & 3;
  int k  = k8 * 8 + m * 2;
  uint32_t lo = f2h(W[k * H_ + j]);
  uint32_t hi = f2h(W[(k + 1) * H_ + j]);
  out[idx] = lo | (hi << 16);
}

// ---------- W_ih pack into MFMA B-fragment order ----------
// Frag (cb, ks): 16 cols (cb*16..), 32 ks (ks*32..). Lane l supplies
// col = cb*16 + (l&15), k = ks*32 + (l>>4)*8 + j (j=0..7) as f16x8 (16 B).
// Stored contiguous: out[((cb*KS + ks)*64 + l)] (uint4) -> 1KB coalesced frag loads.
template<int K>
__global__ __launch_bounds__(512) void pack_wih(const float* __restrict__ W,
                                                uint4* __restrict__ out) {
  constexpr int KS = K / 32;
  int t = blockIdx.x * 512 + threadIdx.x;          // [0, 32*KS*64)
  int l  = t & 63;
  int ks = (t >> 6) % KS;
  int cb = t / (64 * KS);
  int c  = cb * 16 + (l & 15);
  int k0 = ks * 32 + ((l >> 4) & 3) * 8;
  uint4 u;
  u.x = f2h(W[(k0 + 0) * H_ + c]) | (f2h(W[(k0 + 1) * H_ + c]) << 16);
  u.y = f2h(W[(k0 + 2) * H_ + c]) | (f2h(W[(k0 + 3) * H_ + c]) << 16);
  u.z = f2h(W[(k0 + 4) * H_ + c]) | (f2h(W[(k0 + 5) * H_ + c]) << 16);
  u.w = f2h(W[(k0 + 6) * H_ + c]) | (f2h(W[(k0 + 7) * H_ + c]) << 16);
  out[t] = u;
}

// ---------- MFMA f16 GEMM: Y[64 rows/block] = A @ W + bias ----------
// 512 threads = 8 waves: wave = 4 row-groups x 2 col-halves.
// A (fp32) staged -> f16 LDS, XOR-swizzled (byte ^= (row&7)<<4) so A-frag
// ds_read_b128 (lanes 0-15 = rows 0-15, same k) spreads across 8 bank slots.
// B streamed from L2 in fragment order (pack_wih). acc 16 frags = 64 VGPR/wave.
// In-place safe (A==Y): block stages ALL K cols of its own 64 rows before
// any write, and writes only those rows.
template<int K>
__global__ __launch_bounds__(512) void gemm_mfma(const float* A,
    const uint4* __restrict__ WT, const float* __restrict__ bias, float* Y) {
  constexpr int KS = K / 32;
  __shared__ __align__(16) char As[64 * K * 2];    // f16, swizzled
  const int tid = threadIdx.x;
  const size_t row0 = (size_t)blockIdx.x * 64;

  // stage A: 64 rows x K fp32 -> f16 LDS
  const float4* Ab4 = (const float4*)(A + row0 * K);
  #pragma unroll
  for (int it = 0; it < K / 32; ++it) {
    int i4 = tid + it * 512;                       // float4 index
    int fi = i4 * 4;
    int row = fi / K;
    int kk  = fi - row * K;
    float4 v = Ab4[i4];
    uint2 u;
    u.x = f2h(v.x) | (f2h(v.y) << 16);
    u.y = f2h(v.z) | (f2h(v.w) << 16);
    int off = row * (2 * K) + ((kk * 2) ^ ((row & 7) << 4));
    *(uint2*)(As + off) = u;
  }
  __syncthreads();

  const int lane = tid & 63;
  const int wv   = tid >> 6;
  const int rw   = wv >> 1;                        // row group 0..3 (16 rows)
  const int ch   = wv & 1;                         // col half 0..1 (256 cols)

  f32x4 acc[16];
  #pragma unroll
  for (int cf = 0; cf < 16; ++cf) {
    float bz = bias[ch * 256 + cf * 16 + (lane & 15)];
    acc[cf] = (f32x4){bz, bz, bz, bz};
  }

  const int arow = rw * 16 + (lane & 15);
  const int abase = arow * (2 * K);
  const int aswz = (arow & 7) << 4;
  for (int ks = 0; ks < KS; ++ks) {
    int kbyte = ks * 64 + ((lane >> 4) & 3) * 16;
    f16x8 af = *(const f16x8*)(As + abase + (kbyte ^ aswz));
    #pragma unroll
    for (int cf = 0; cf < 16; ++cf) {
      uint4 bu = WT[(size_t)((ch * 16 + cf) * KS + ks) * 64 + lane];
      f16x8 bf = __builtin_bit_cast(f16x8, bu);
      acc[cf] = __builtin_amdgcn_mfma_f32_16x16x32_f16(af, bf, acc[cf], 0, 0, 0);
    }
  }
  __syncthreads();                                 // all A reads done before write (in-place)

  // C/D layout (guide m89): col = lane&15, row = (lane>>4)*4 + reg
  const int wrow = rw * 16 + ((lane >> 4) & 3) * 4;
  #pragma unroll
  for (int cf = 0; cf < 16; ++cf) {
    int col = ch * 256 + cf * 16 + (lane & 15);
    float* Yp = Y + (row0 + wrow) * H_ + col;
    #pragma unroll
    for (int r = 0; r < 4; ++r) Yp[r * H_] = acc[cf][r];
  }
}

// ---------- scan (unchanged from R10: R2 topology + ping-pong h) ----------
#define ROW(m, WEXPR) { uint4 w_ = (WEXPR); \
  a0 = dot2(w_.x, hsel<4*(m)+0>(h0,h1,h2,h3), a0); \
  a1 = dot2(w_.y, hsel<4*(m)+1>(h0,h1,h2,h3), a1); \
  a2 = dot2(w_.z, hsel<4*(m)+2>(h0,h1,h2,h3), a2); \
  a3 = dot2(w_.w, hsel<4*(m)+3>(h0,h1,h2,h3), a3); }

#define BATCH_LOAD(OFF0, OFF1, OFF2, OFF3) \
  asm volatile("s_load_dwordx16 %0, %4, " OFF0 "\n\t" \
               "s_load_dwordx16 %1, %4, " OFF1 "\n\t" \
               "s_load_dwordx16 %2, %4, " OFF2 "\n\t" \
               "s_load_dwordx16 %3, %4, " OFF3 "\n\t" \
               "s_waitcnt lgkmcnt(0)" \
               : "=&s"(h0), "=&s"(h1), "=&s"(h2), "=&s"(h3) : "s"(hbase)); \
  __builtin_amdgcn_sched_barrier(0);

#define CONS16(W0)  ROW(0,W0(0))  ROW(1,W0(1))  ROW(2,W0(2))  ROW(3,W0(3)) \
                    ROW(4,W0(4))  ROW(5,W0(5))  ROW(6,W0(6))  ROW(7,W0(7)) \
                    ROW(8,W0(8))  ROW(9,W0(9))  ROW(10,W0(10)) ROW(11,W0(11)) \
                    ROW(12,W0(12)) ROW(13,W0(13)) ROW(14,W0(14)) ROW(15,W0(15))

#define WREG0(m) wrv[m]
#define WREG1(m) wrv[16 + (m)]
#define WLDS(m)  WL[(m) * 512 + j]
#define WSTR(m)  g[m]

__global__ __launch_bounds__(512, 2) void rnn_scan(float* Y,
    const uint4* __restrict__ Wp, ushort* __restrict__ hb16,
    float* __restrict__ hn) {
  __shared__ uint4 WL[16 * 512];                   // 128 KB: slabs 32..47
  const int j = threadIdx.x;
  float* Yb = Y + (size_t)blockIdx.x * (T_ * H_);
  ushort* hp0 = hb16 + blockIdx.x * (2 * H_);      // ping
  ushort* hp1 = hp0 + H_;                          // pong

  uint4 wrv[32];                                   // slabs 0..31 (compiler-managed)
  #pragma unroll
  for (int m = 0; m < 32; ++m) wrv[m] = Wp[m * H_ + j];
  #pragma unroll
  for (int it = 0; it < 16; ++it) WL[it * 512 + j] = Wp[(32 + it) * 512 + j];

  float xp0 = Yb[j];
  float v = fast_tanh(xp0);
  hp0[j] = (ushort)f2h(v);
  Yb[j] = v;
  const uint64_t hb0 = (uint64_t)(uintptr_t)hp0;
  const uint64_t hb1 = (uint64_t)(uintptr_t)hp1;
  asm volatile("s_waitcnt vmcnt(0) lgkmcnt(0)\n\ts_barrier\n\ts_dcache_inv" ::: "memory");

  for (int t = 1; t < T_; ++t) {
    const uint64_t hbase = (t & 1) ? hb0 : hb1;    // read h(t-1)
    ushort* hst = (t & 1) ? hp1 : hp0;             // store h(t)
    float xpt = Yb[t * H_ + j];
    uint4 g[16];
    #pragma unroll
    for (int m = 0; m < 16; ++m) g[m] = Wp[(48 + m) * H_ + j];
    float a0 = 0.f, a1 = 0.f, a2 = 0.f, a3 = 0.f;
    sv16 h0, h1, h2, h3;

    BATCH_LOAD("0x0", "0x40", "0x80", "0xc0")
    CONS16(WREG0)
    BATCH_LOAD("0x100", "0x140", "0x180", "0x1c0")
    CONS16(WREG1)
    BATCH_LOAD("0x200", "0x240", "0x280", "0x2c0")
    CONS16(WLDS)
    BATCH_LOAD("0x300", "0x340", "0x380", "0x3c0")
    CONS16(WSTR)

    float s = xpt + ((a0 + a1) + (a2 + a3));
    v = fast_tanh(s);
    hst[j] = (ushort)f2h(v);
    asm volatile("s_waitcnt vmcnt(0)\n\ts_barrier\n\ts_dcache_inv" ::: "memory");
    Yb[t * H_ + j] = v;
  }
  hn[blockIdx.x * H_ + j] = v;
}

extern "C" void kernel_launch(void* const* d_in, const int* in_sizes, int n_in,
                              void* d_out, int out_size, void* d_ws, size_t ws_size,
                              hipStream_t stream) {
  const float* x     = (const float*)d_in[0];
  const float* W_ih0 = (const float*)d_in[1];
  const float* W_hh0 = (const float*)d_in[2];
  const float* b0    = (const float*)d_in[3];
  const float* W_ih1 = (const float*)d_in[4];
  const float* W_hh1 = (const float*)d_in[5];
  const float* b1    = (const float*)d_in[6];

  float* Y  = (float*)d_out;                        // [64][1024][512]
  float* hn = Y + (size_t)B_ * T_ * H_;             // [2][64][512]
  uint32_t* Wp = (uint32_t*)d_ws;                   // [0,512K): f16 W_hh (per layer)
  ushort* hbuf = (ushort*)((char*)d_ws + 512 * 1024);   // [512K,640K): ping-pong h
  uint4* WT  = (uint4*)((char*)d_ws + 640 * 1024);      // [640K,1152K): W_ih B-frags

  // layer 0
  pack_whh<<<512, 256, 0, stream>>>(W_hh0, Wp);
  pack_wih<I_><<<32, 512, 0, stream>>>(W_ih0, WT);  // 32*8*64 = 16384 frag-lanes
  gemm_mfma<I_><<<1024, 512, 0, stream>>>(x, WT, b0, Y);
  rnn_scan<<<B_, H_, 0, stream>>>(Y, (const uint4*)Wp, hbuf, hn);
  // layer 1
  pack_whh<<<512, 256, 0, stream>>>(W_hh1, Wp);
  pack_wih<H_><<<64, 512, 0, stream>>>(W_ih1, WT);  // 32*16*64 = 32768 frag-lanes
  gemm_mfma<H_><<<1024, 512, 0, stream>>>(Y, WT, b1, Y);
  rnn_scan<<<B_, H_, 0, stream>>>(Y, (const uint4*)Wp, hbuf, hn + B_ * H_);
}